// Round 10
// baseline (100.536 us; speedup 1.0000x reference)
//
#include <hip/hip_runtime.h>
#include <hip/hip_bf16.h>

// Problem constants (from reference)
#define BATCH   8
#define MROWS   2048      // C*P = 4*512
#define DIM_Z   512
#define DIM_G   1024
#define EDIM    128
#define EPS     1e-6f
#define BK      64        // GEMM K-step

typedef unsigned short u16;
typedef unsigned int   u32;
typedef __attribute__((ext_vector_type(8))) short bf16x8;
typedef __attribute__((ext_vector_type(4))) float f32x4;
typedef __attribute__((ext_vector_type(4))) float fvec4;   // ext-vector for NT builtins
typedef __attribute__((ext_vector_type(4))) u32   u32x4;

// f32 -> bf16 round-to-nearest-even (bit trick; inputs are finite)
__device__ __forceinline__ u16 f2b(float f) {
    u32 x = __float_as_uint(f);
    u32 r = x + 0x7fffu + ((x >> 16) & 1u);
    return (u16)(r >> 16);
}

// async global->LDS, 16B per lane, dest = wave-uniform base + lane*16
#define GLD16(gsrc, ldst) __builtin_amdgcn_global_load_lds( \
    (const __attribute__((address_space(1))) unsigned int*)(gsrc), \
    (__attribute__((address_space(3))) unsigned int*)(ldst), 16, 0, 0)

#define WAITVM6()   asm volatile("s_waitcnt vmcnt(6)" ::: "memory")
#define WAITVM0()   asm volatile("s_waitcnt vmcnt(0)" ::: "memory")
#define MEMFENCE()  asm volatile("" ::: "memory")

// ---- kernel 1: u = a_emb @ Wu^T, v = a_emb @ Wv^T (coalesced), + zero rsum ----
__global__ void uv_kernel(const float* __restrict__ emb, const int* __restrict__ idx,
                          const float* __restrict__ Wu, const float* __restrict__ Wv,
                          float* __restrict__ u, float* __restrict__ v,
                          float* __restrict__ rsum) {
    __shared__ float a[EDIM];
    int b = blockIdx.y;
    int t = threadIdx.x;
    if (blockIdx.x == 0)   // zero rsum[b] (runs before GEMM1 in stream order)
        for (int i = t; i < MROWS; i += 256) rsum[(size_t)b * MROWS + i] = 0.f;
    if (t < EDIM) a[t] = emb[(size_t)idx[b] * EDIM + t];
    __syncthreads();
    int tx = t & 31, ty = t >> 5;
    int oBase = blockIdx.x * 256;
    for (int o0 = 0; o0 < 256; o0 += 8) {
        int o = oBase + o0 + ty;
        const float* wrow = (o < DIM_G) ? (Wu + (size_t)o * EDIM)
                                        : (Wv + (size_t)(o - DIM_G) * EDIM);
        float s = 0.f;
#pragma unroll
        for (int q = 0; q < 4; ++q) s += a[q * 32 + tx] * wrow[q * 32 + tx];
        s += __shfl_xor(s, 1, 64);
        s += __shfl_xor(s, 2, 64);
        s += __shfl_xor(s, 4, 64);
        s += __shfl_xor(s, 8, 64);
        s += __shfl_xor(s, 16, 64);
        if (tx == 0) {
            if (o < DIM_G) u[b * DIM_G + o] = s;
            else           v[b * DIM_Z + (o - DIM_G)] = s;
        }
    }
}

// ---- kernel 2: cast qz f32 -> bf16, XCD-aligned (b = h&7): qzb lands dirty in
// the XCD's L2 that GEMM1's batch-b blocks run on. NT loads (single-use). ----
__global__ void cast_kernel(const float* __restrict__ in, u16* __restrict__ out) {
    int h = blockIdx.x;
    int b = h & 7, s = h >> 3;                    // s in [0,512) per batch
    size_t base = (size_t)b * MROWS * DIM_Z;      // elements
    int i = s * 256 + threadIdx.x;                // 8-elem chunk id within batch
    const fvec4* p = (const fvec4*)(in + base) + (size_t)i * 2;
    fvec4 f0 = __builtin_nontemporal_load(p);
    fvec4 f1 = __builtin_nontemporal_load(p + 1);
    union { u16 us[8]; u32x4 v; } o;
    o.us[0] = f2b(f0.x); o.us[1] = f2b(f0.y); o.us[2] = f2b(f0.z); o.us[3] = f2b(f0.w);
    o.us[4] = f2b(f1.x); o.us[5] = f2b(f1.y); o.us[6] = f2b(f1.z); o.us[7] = f2b(f1.w);
    ((u32x4*)(out + base))[i] = o.v;
}

// -- kernel 3: W[b,g,d] = W_base + u*v -> bf16 (+ transposed WT), b = h&7 --
__global__ void wpack_kernel(const float* __restrict__ Wbase,
                             const float* __restrict__ u, const float* __restrict__ v,
                             u16* __restrict__ W, u16* __restrict__ WT) {
    __shared__ u16 tile[32][33];
    int h = blockIdx.x;
    int b = h & 7, t8 = h >> 3;          // t8 in [0,512)
    int d0 = (t8 & 15) * 32, g0 = (t8 >> 4) * 32;
    int tx = threadIdx.x, ty = threadIdx.y;
    float vb = v[b * DIM_Z + d0 + tx];
#pragma unroll
    for (int j = 0; j < 4; ++j) {
        int g = g0 + ty + j * 8;
        u16 h16 = f2b(Wbase[(size_t)g * DIM_Z + d0 + tx] + u[b * DIM_G + g] * vb);
        W[((size_t)b * DIM_G + g) * DIM_Z + d0 + tx] = h16;
        tile[ty + j * 8][tx] = h16;
    }
    __syncthreads();
#pragma unroll
    for (int j = 0; j < 4; ++j)
        WT[((size_t)b * DIM_Z + d0 + ty + j * 8) * DIM_G + g0 + tx] =
            tile[tx][ty + j * 8];
}

// ---------------- GEMM: C[m,n] = sum_k A[m,k] * Bt[n,k], per-batch ----------------
// LEAD-2 PIPELINE (T3+T4): tile 128x256, BK=64, 8 waves (2M x 4N, 64x64/wave),
// TRIPLE-buffered LDS (buf = tile%3, 144 KB). Per iteration t:
//   vmcnt(6)   [drains everything older than tile t+1's 6 loads -> tile t landed;
//               tile t was issued 2 iterations ago = ~2800cy of cover]
//   s_barrier  [all waves' tile-t data landed]
//   stage(t+2) [6 gld_lds -> buf[(t+2)%3]; its previous reader (tile t-1)
//               finished before THIS barrier -> no W-after-R hazard]
//   ds_read + 32 MFMA (2 ksteps, setprio-wrapped)
// ONE barrier per iteration; vmcnt never 0 until the tail.
// Chunk XOR swizzle c^(row&7) on global source + same XOR on ds_read (rule #21;
// measured 0 bank conflicts r4-r9). XCD decode: b = h&7, j = h>>3 n-fastest.
// EPI=0: relu -> bf16 store (qg, normal: GEMM2 wants it L2-hot) + rsum atomics.
// EPI=1: scale by 1/max(rsum[m],eps) -> f32 NT-store (out, never re-read).
template <int EPI, int NTL>
__global__ __launch_bounds__(512, 1)
void gemm_bt(const u16* __restrict__ Aall, const u16* __restrict__ Btall,
             void* __restrict__ Call, float* __restrict__ rsum,
             int M, int N, int K) {
    __shared__ u16 As[3][128 * BK];   // 3 x 16 KB
    __shared__ u16 Bs[3][256 * BK];   // 3 x 32 KB   (total 144 KB)

    int h = blockIdx.x;
    int b = h & 7;
    int j = h >> 3;
    int mBase = (j >> NTL) * 128;
    int nBase = (j & ((1 << NTL) - 1)) * 256;

    const u16* A  = Aall  + (size_t)b * M * K;
    const u16* Bt = Btall + (size_t)b * N * K;
    int tid  = threadIdx.x;
    int lane = tid & 63, wid = tid >> 6;
    int wm = wid >> 2, wn = wid & 3;            // 2M x 4N wave grid
    int lr = lane & 15, lg = lane >> 4;

    f32x4 acc[4][4] = {};

    // staging geometry: slot s = r*512 + tid; row = r*64 + (tid>>3); chunk c'=s&7;
    // physical chunk cw = c' ^ (row&7)  (row&7 == (tid>>3)&7 for all r).
    int sRow = tid >> 3;                         // 0..63
    int cw   = (tid & 7) ^ (sRow & 7);
    const u16* aSrc = A  + (size_t)(mBase + sRow) * K + cw * 8;
    const u16* bSrc = Bt + (size_t)(nBase + sRow) * K + cw * 8;

    int nIter = K / BK;

    auto stage = [&](int tt) {                   // tile tt -> buf tt%3
        int buf = tt % 3;
        int k0  = tt * BK;
#pragma unroll
        for (int r = 0; r < 2; ++r)              // A: 128 rows
            GLD16(aSrc + (size_t)r * 64 * K + k0,
                  &As[buf][(r * 512 + wid * 64) * 8]);
#pragma unroll
        for (int r = 0; r < 4; ++r)              // B: 256 rows
            GLD16(bSrc + (size_t)r * 64 * K + k0,
                  &Bs[buf][(r * 512 + wid * 64) * 8]);
    };

    // prologue: tiles 0 and 1 in flight (12 loads)
    stage(0);
    stage(1);

    for (int t = 0; t < nIter; ++t) {
        if (t + 1 < nIter) { WAITVM6(); }        // tile t landed; t+1's 6 fly on
        else               { WAITVM0(); }        // tail drain
        __builtin_amdgcn_s_barrier();
        MEMFENCE();
        if (t + 2 < nIter) stage(t + 2);         // issue-early, 2-iteration lead
        int buf = t % 3;
#pragma unroll
        for (int ks = 0; ks < 2; ++ks) {
            bf16x8 af[4], bfr[4];
#pragma unroll
            for (int mi = 0; mi < 4; ++mi) {
                int row = wm * 64 + mi * 16 + lr;
                int cq  = (ks * 4 + lg) ^ (row & 7);
                af[mi] = *(const bf16x8*)&As[buf][row * 64 + cq * 8];
            }
#pragma unroll
            for (int ni = 0; ni < 4; ++ni) {
                int row = wn * 64 + ni * 16 + lr;
                int cq  = (ks * 4 + lg) ^ (row & 7);
                bfr[ni] = *(const bf16x8*)&Bs[buf][row * 64 + cq * 8];
            }
            __builtin_amdgcn_s_setprio(1);
#pragma unroll
            for (int mi = 0; mi < 4; ++mi)
#pragma unroll
                for (int ni = 0; ni < 4; ++ni)
                    acc[mi][ni] = __builtin_amdgcn_mfma_f32_16x16x32_bf16(
                        af[mi], bfr[ni], acc[mi][ni], 0, 0, 0);
            __builtin_amdgcn_s_setprio(0);
        }
        MEMFENCE();
    }

    int mw = mBase + wm * 64, nw = nBase + wn * 64;
    if (EPI == 0) {
        u16* C = (u16*)Call + (size_t)b * M * N;
#pragma unroll
        for (int mi = 0; mi < 4; ++mi)
#pragma unroll
            for (int r = 0; r < 4; ++r) {
                int m = mw + mi * 16 + lg * 4 + r;
                float vals[4];
                float s = 0.f;
#pragma unroll
                for (int ni = 0; ni < 4; ++ni) {
                    vals[ni] = fmaxf(acc[mi][ni][r], 0.f);
                    s += vals[ni];
                }
#pragma unroll
                for (int ni = 0; ni < 4; ++ni)
                    C[(size_t)m * N + nw + ni * 16 + lr] = f2b(vals[ni]);
                // reduce across the 16 lr-lanes (same lg => same m)
                s += __shfl_xor(s, 1, 64);
                s += __shfl_xor(s, 2, 64);
                s += __shfl_xor(s, 4, 64);
                s += __shfl_xor(s, 8, 64);
                if (lr == 0) atomicAdd(&rsum[(size_t)b * M + m], s);
            }
    } else {
        float* C = (float*)Call + (size_t)b * M * N;
        const float* rs = rsum + (size_t)b * M;
#pragma unroll
        for (int mi = 0; mi < 4; ++mi)
#pragma unroll
            for (int r = 0; r < 4; ++r) {
                int m = mw + mi * 16 + lg * 4 + r;
                float inv = 1.f / fmaxf(rs[m], EPS);
#pragma unroll
                for (int ni = 0; ni < 4; ++ni)
                    __builtin_nontemporal_store(acc[mi][ni][r] * inv,
                        &C[(size_t)m * N + nw + ni * 16 + lr]);
            }
    }
}

extern "C" void kernel_launch(void* const* d_in, const int* in_sizes, int n_in,
                              void* d_out, int out_size, void* d_ws, size_t ws_size,
                              hipStream_t stream) {
    const float* qz    = (const float*)d_in[0];
    const int*   attr  = (const int*)d_in[1];
    const float* Wbase = (const float*)d_in[2];
    const float* emb   = (const float*)d_in[3];
    const float* Wu    = (const float*)d_in[4];
    const float* Wv    = (const float*)d_in[5];
    float* out = (float*)d_out;

    // workspace carve-up (all 256B aligned)
    char* ws = (char*)d_ws;
    size_t off = 0;
    auto alloc = [&](size_t bytes) -> void* {
        void* p = ws + off;
        off = (off + bytes + 255) & ~(size_t)255;
        return p;
    };
    float* u    = (float*)alloc((size_t)BATCH * DIM_G * 4);
    float* v    = (float*)alloc((size_t)BATCH * DIM_Z * 4);
    float* rsum = (float*)alloc((size_t)BATCH * MROWS * 4);
    u16*   qzb  = (u16*)  alloc((size_t)BATCH * MROWS * DIM_Z * 2);
    u16*   W    = (u16*)  alloc((size_t)BATCH * DIM_G * DIM_Z * 2);
    u16*   WT   = (u16*)  alloc((size_t)BATCH * DIM_G * DIM_Z * 2);
    u16*   qg   = (u16*)  alloc((size_t)BATCH * MROWS * DIM_G * 2);
    if (off > ws_size) return;  // fail loudly (zero output) rather than corrupt

    uv_kernel<<<dim3(6, BATCH), dim3(256), 0, stream>>>(emb, attr, Wu, Wv, u, v, rsum);

    // cast qz -> bf16 (XCD-aligned so qzb is L2-dirty on the right XCD)
    cast_kernel<<<dim3(4096), dim3(256), 0, stream>>>(qz, qzb);

    wpack_kernel<<<dim3(4096), dim3(32, 8), 0, stream>>>(Wbase, u, v, W, WT);

    // GEMM1: qg = relu(qzb @ W^T) + rsum epilogue.
    // tiles: 16 m x 4 n x 8 b = 512 blocks (NTL=2)
    gemm_bt<0, 2><<<dim3(512), dim3(512), 0, stream>>>(
        qzb, W, qg, rsum, MROWS, DIM_G, DIM_Z);

    // GEMM2: out = (qg @ WT^T) / max(rsum,eps).
    // tiles: 16 m x 2 n x 8 b = 256 blocks (NTL=1)
    gemm_bt<1, 1><<<dim3(256), dim3(512), 0, stream>>>(
        qg, WT, out, rsum, MROWS, DIM_Z, DIM_G);
}